// Round 1
// baseline (453.031 us; speedup 1.0000x reference)
//
#include <hip/hip_runtime.h>

#define TT 1024
#define FF 8

// quad_perm broadcast: every lane of a quad gets the value from quad-lane K
#define QB(v,K) __int_as_float(__builtin_amdgcn_mov_dpp(__float_as_int(v), 85*(K), 0xF, 0xF, true))
// within each 16-lane group, read from lane 4*K (src = (lane & 0x10) | 4K per 32-half)
#define HSW(v,K) __int_as_float(__builtin_amdgcn_ds_swizzle(__float_as_int(v), (((4*(K))<<5)|0x10)))

__device__ __forceinline__ float rcp_(float x){ return __builtin_amdgcn_rcpf(x); }
__device__ __forceinline__ float ex2_(float x){ return __builtin_amdgcn_exp2f(x); }

__global__ __launch_bounds__(256) void lstm_ae_kernel(
    const float* __restrict__ X,
    const float* __restrict__ eWih0, const float* __restrict__ eWhh0, const float* __restrict__ eb0,
    const float* __restrict__ eWih1, const float* __restrict__ eWhh1, const float* __restrict__ eb1,
    const float* __restrict__ dWih0, const float* __restrict__ dWhh0, const float* __restrict__ db0,
    const float* __restrict__ dWih1, const float* __restrict__ dWhh1, const float* __restrict__ db1,
    const float* __restrict__ fcW,  const float* __restrict__ fcb,
    float* __restrict__ out)
{
  const int tid = blockIdx.x * blockDim.x + threadIdx.x;
  const int e   = tid >> 4;              // batch element (4096 total)
  const int l   = threadIdx.x & 15;      // lane in 16-group
  const int j   = l >> 2;                // hidden unit 0..3
  const int g   = l & 3;                 // gate 0=i 1=f 2=g 3=o
  const int r   = g * 4 + j;             // weight row (PyTorch i,f,g,o order)
  const bool isT = (g == 2);
  const float Sact = isT ? -2.8853900817779268f : -1.4426950408889634f; // -2log2e / -log2e
  const float actA = isT ? 2.f : 1.f;
  const float actB = isT ? -1.f : 0.f;
  const float TS   = -2.8853900817779268f;

  // ---------------- per-lane weight preload (scaled by Sact) ----------------
  float ewx[8], ewh0[4], ewi1[4], ewh1[4];
#pragma unroll
  for (int k = 0; k < 8; ++k) ewx[k] = Sact * eWih0[r*8 + k];
#pragma unroll
  for (int k = 0; k < 4; ++k) {
    ewh0[k] = Sact * eWhh0[r*4 + k];
    ewi1[k] = Sact * eWih1[r*4 + k];
    ewh1[k] = Sact * eWhh1[r*4 + k];
  }
  const float eb0s = Sact * eb0[r];
  const float eb1s = Sact * eb1[r];

  float dwh0[4], dwi1[4], dwh1[4], wpp[4], dw0row[8];
#pragma unroll
  for (int k = 0; k < 4; ++k) {
    dwh0[k] = Sact * dWhh0[r*4 + k];
    dwi1[k] = Sact * dWih1[r*4 + k];
    dwh1[k] = Sact * dWhh1[r*4 + k];
  }
#pragma unroll
  for (int k = 0; k < 8; ++k) dw0row[k] = dWih0[r*8 + k];
  // fused: W'' = dec_Wih0 @ fc_W  [16,4];  b'' = db0 + dec_Wih0 @ fc_b
#pragma unroll
  for (int k = 0; k < 4; ++k) {
    float s = 0.f;
#pragma unroll
    for (int f = 0; f < 8; ++f) s = fmaf(dw0row[f], fcW[f*4 + k], s);
    wpp[k] = Sact * s;
  }
  float bcorr = 0.f;
#pragma unroll
  for (int f = 0; f < 8; ++f) bcorr = fmaf(dw0row[f], fcb[f], bcorr);
  const float dbias0 = Sact * db0[r];            // first decoder step: x0 == 0
  const float dbiasR = Sact * (db0[r] + bcorr);  // later steps: fused fc bias
  const float db1s   = Sact * db1[r];

  const int fr = l & 7;
  float fw[4];
#pragma unroll
  for (int k = 0; k < 4; ++k) fw[k] = fcW[fr*4 + k];
  const float fbr = fcb[fr];

  // ---------------- state ----------------
  float h0[4] = {0,0,0,0}, h1[4] = {0,0,0,0};
  float c0 = 0.f, c1 = 0.f;

  const float* xp = X + (size_t)e * (TT*FF);
  float4 pa[4], pb[4];
#pragma unroll
  for (int u = 0; u < 4; ++u) {
    pa[u] = *(const float4*)(xp + u*8);
    pb[u] = *(const float4*)(xp + u*8 + 4);
  }

  auto encStep = [&](const float4 xlo, const float4 xhi) {
    // layer 0: z = x·Wih0[r,:] + h0·Whh0[r,:] + b0   (pre-scaled)
    float za = fmaf(xlo.x, ewx[0], eb0s);
    za = fmaf(xlo.y, ewx[1], za);
    za = fmaf(xlo.z, ewx[2], za);
    za = fmaf(xlo.w, ewx[3], za);
    float zb = xhi.x * ewx[4];
    zb = fmaf(xhi.y, ewx[5], zb);
    zb = fmaf(xhi.z, ewx[6], zb);
    zb = fmaf(xhi.w, ewx[7], zb);
    za = fmaf(h0[0], ewh0[0], za);
    zb = fmaf(h0[1], ewh0[1], zb);
    za = fmaf(h0[2], ewh0[2], za);
    zb = fmaf(h0[3], ewh0[3], zb);
    float z = za + zb;
    float a = fmaf(actA, rcp_(1.f + ex2_(z)), actB);
    float ai = QB(a,0), af = QB(a,1), ag = QB(a,2), ao = QB(a,3);
    c0 = fmaf(af, c0, ai*ag);
    float th = fmaf(2.f, rcp_(1.f + ex2_(TS*c0)), -1.f);
    float hn = ao * th;
    float n0 = HSW(hn,0), n1 = HSW(hn,1), n2 = HSW(hn,2), n3 = HSW(hn,3);
    // layer 1: z1 = h0n·Wih1[r,:] + h1·Whh1[r,:] + b1
    float wa = fmaf(h1[0], ewh1[0], eb1s);
    wa = fmaf(h1[1], ewh1[1], wa);
    float wb = h1[2] * ewh1[2];
    wb = fmaf(h1[3], ewh1[3], wb);
    wa = fmaf(n0, ewi1[0], wa);
    wb = fmaf(n1, ewi1[1], wb);
    wa = fmaf(n2, ewi1[2], wa);
    wb = fmaf(n3, ewi1[3], wb);
    h0[0]=n0; h0[1]=n1; h0[2]=n2; h0[3]=n3;
    float z1 = wa + wb;
    float a1 = fmaf(actA, rcp_(1.f + ex2_(z1)), actB);
    float bi = QB(a1,0), bf = QB(a1,1), bg = QB(a1,2), bo = QB(a1,3);
    c1 = fmaf(bf, c1, bi*bg);
    float th1 = fmaf(2.f, rcp_(1.f + ex2_(TS*c1)), -1.f);
    float hn1 = bo * th1;
    h1[0]=HSW(hn1,0); h1[1]=HSW(hn1,1); h1[2]=HSW(hn1,2); h1[3]=HSW(hn1,3);
  };

  // ---------------- encoder: 1024 steps, x prefetched 4 deep ----------------
  for (int tb = 0; tb < TT - 4; tb += 4) {
#pragma unroll
    for (int u = 0; u < 4; ++u) {
      encStep(pa[u], pb[u]);
      pa[u] = *(const float4*)(xp + (tb + 4 + u)*8);
      pb[u] = *(const float4*)(xp + (tb + 4 + u)*8 + 4);
    }
  }
#pragma unroll
  for (int u = 0; u < 4; ++u) encStep(pa[u], pb[u]);

  // ---------------- decoder: 1024 autoregressive steps ----------------
  float rh[4] = {0,0,0,0};           // relu(h1_{t-1}); x0==0 -> rh=0, bias=db0
  float biasCur = dbias0;
  float* op = out + (size_t)e * (TT*FF) + (TT-1)*FF + fr;

  for (int t = 0; t < TT; ++t) {
    // layer 0 (fc fused): z = rh·W'' + h0·Whh0 + bias
    float za = fmaf(rh[0], wpp[0], biasCur);
    za = fmaf(rh[1], wpp[1], za);
    float zb = rh[2] * wpp[2];
    zb = fmaf(rh[3], wpp[3], zb);
    za = fmaf(h0[0], dwh0[0], za);
    zb = fmaf(h0[1], dwh0[1], zb);
    za = fmaf(h0[2], dwh0[2], za);
    zb = fmaf(h0[3], dwh0[3], zb);
    float z = za + zb;
    float a = fmaf(actA, rcp_(1.f + ex2_(z)), actB);
    float ai = QB(a,0), af = QB(a,1), ag = QB(a,2), ao = QB(a,3);
    c0 = fmaf(af, c0, ai*ag);
    float th = fmaf(2.f, rcp_(1.f + ex2_(TS*c0)), -1.f);
    float hn = ao * th;
    float n0 = HSW(hn,0), n1 = HSW(hn,1), n2 = HSW(hn,2), n3 = HSW(hn,3);
    // layer 1
    float wa = fmaf(h1[0], dwh1[0], db1s);
    wa = fmaf(h1[1], dwh1[1], wa);
    float wb = h1[2] * dwh1[2];
    wb = fmaf(h1[3], dwh1[3], wb);
    wa = fmaf(n0, dwi1[0], wa);
    wb = fmaf(n1, dwi1[1], wb);
    wa = fmaf(n2, dwi1[2], wa);
    wb = fmaf(n3, dwi1[3], wb);
    h0[0]=n0; h0[1]=n1; h0[2]=n2; h0[3]=n3;
    float z1 = wa + wb;
    float a1 = fmaf(actA, rcp_(1.f + ex2_(z1)), actB);
    float bi = QB(a1,0), bf = QB(a1,1), bg = QB(a1,2), bo = QB(a1,3);
    c1 = fmaf(bf, c1, bi*bg);
    float th1 = fmaf(2.f, rcp_(1.f + ex2_(TS*c1)), -1.f);
    float hn1 = bo * th1;
    h1[0]=HSW(hn1,0); h1[1]=HSW(hn1,1); h1[2]=HSW(hn1,2); h1[3]=HSW(hn1,3);
    // rh for next step's fused layer0 AND this step's y
    rh[0]=fmaxf(h1[0],0.f); rh[1]=fmaxf(h1[1],0.f);
    rh[2]=fmaxf(h1[2],0.f); rh[3]=fmaxf(h1[3],0.f);
    float y = fmaf(rh[0], fw[0], fbr);
    y = fmaf(rh[1], fw[1], y);
    y = fmaf(rh[2], fw[2], y);
    y = fmaf(rh[3], fw[3], y);
    if (l < 8) *op = y;               // out[e, T-1-t, fr]
    op -= FF;
    biasCur = dbiasR;
  }
}

extern "C" void kernel_launch(void* const* d_in, const int* in_sizes, int n_in,
                              void* d_out, int out_size, void* d_ws, size_t ws_size,
                              hipStream_t stream) {
  const float* X      = (const float*)d_in[0];
  const float* eWih0  = (const float*)d_in[1];
  const float* eWhh0  = (const float*)d_in[2];
  const float* eb0    = (const float*)d_in[3];
  const float* eWih1  = (const float*)d_in[4];
  const float* eWhh1  = (const float*)d_in[5];
  const float* eb1    = (const float*)d_in[6];
  const float* dWih0  = (const float*)d_in[7];
  const float* dWhh0  = (const float*)d_in[8];
  const float* db0    = (const float*)d_in[9];
  const float* dWih1  = (const float*)d_in[10];
  const float* dWhh1  = (const float*)d_in[11];
  const float* db1    = (const float*)d_in[12];
  const float* fcW    = (const float*)d_in[13];
  const float* fcb    = (const float*)d_in[14];
  float* out = (float*)d_out;

  // 4096 elements x 16 lanes = 65536 threads
  dim3 grid(256), block(256);
  lstm_ae_kernel<<<grid, block, 0, stream>>>(X, eWih0, eWhh0, eb0, eWih1, eWhh1, eb1,
                                             dWih0, dWhh0, db0, dWih1, dWhh1, db1,
                                             fcW, fcb, out);
}

// Round 2
// 368.408 us; speedup vs baseline: 1.2297x; 1.2297x over previous
//
#include <hip/hip_runtime.h>

#define TT 1024
#define FF 8

// quad_perm broadcast: every lane of a quad gets the value from quad-lane K
#define QB(v,K) __int_as_float(__builtin_amdgcn_mov_dpp(__float_as_int(v), 85*(K), 0xF, 0xF, true))
// row rotate (16-lane row) by 4/8/12 lanes — cross-quad exchange, VALU pipe
#define ROR4F(v)  __int_as_float(__builtin_amdgcn_mov_dpp(__float_as_int(v), 0x124, 0xF, 0xF, true))
#define ROR8F(v)  __int_as_float(__builtin_amdgcn_mov_dpp(__float_as_int(v), 0x128, 0xF, 0xF, true))
#define ROR12F(v) __int_as_float(__builtin_amdgcn_mov_dpp(__float_as_int(v), 0x12C, 0xF, 0xF, true))

__device__ __forceinline__ float rcp_(float x){ return __builtin_amdgcn_rcpf(x); }
__device__ __forceinline__ float ex2_(float x){ return __builtin_amdgcn_exp2f(x); }

__global__ __launch_bounds__(256) void lstm_ae_kernel(
    const float* __restrict__ X,
    const float* __restrict__ eWih0, const float* __restrict__ eWhh0, const float* __restrict__ eb0,
    const float* __restrict__ eWih1, const float* __restrict__ eWhh1, const float* __restrict__ eb1,
    const float* __restrict__ dWih0, const float* __restrict__ dWhh0, const float* __restrict__ db0,
    const float* __restrict__ dWih1, const float* __restrict__ dWhh1, const float* __restrict__ db1,
    const float* __restrict__ fcW,  const float* __restrict__ fcb,
    float* __restrict__ out)
{
  const int tid = blockIdx.x * blockDim.x + threadIdx.x;
  const int e   = tid >> 4;              // batch element
  const int l   = threadIdx.x & 15;      // lane in 16-group
  const int q   = l >> 2;                // hidden unit (quad) 0..3
  const int g   = l & 3;                 // gate 0=i 1=f 2=g 3=o
  const int r   = g * 4 + q;             // weight row (PyTorch i,f,g,o order)
  const bool isT = (g == 2);
  const float Sact = isT ? -2.8853900817779268f : -1.4426950408889634f; // -2log2e / -log2e
  const float actA = isT ? 2.f : 1.f;
  const float actB = isT ? -1.f : 0.f;
  const float TS   = -2.8853900817779268f;

  // ---- DPP row_ror direction probe (makes the rotated-tuple layout direction-proof) ----
  int rot4 = __builtin_amdgcn_mov_dpp(l, 0x124, 0xF, 0xF, true);
  const int d = (rot4 == ((l + 12) & 15)) ? 3 : 1;
  int perm[4];
  perm[0] = q;
  perm[1] = (q + d) & 3;
  perm[2] = (q + 2) & 3;       // same under either convention
  perm[3] = (q + 3 * d) & 3;

  // ---------------- per-lane weight preload (scaled by Sact, hidden-dots permuted) ----------------
  float ewx[8];
#pragma unroll
  for (int k = 0; k < 8; ++k) ewx[k] = Sact * eWih0[r*8 + k];
  float ewh0p[4], ewi1p[4], ewh1p[4];
#pragma unroll
  for (int k = 0; k < 4; ++k) {
    ewh0p[k] = Sact * eWhh0[r*4 + perm[k]];
    ewi1p[k] = Sact * eWih1[r*4 + perm[k]];
    ewh1p[k] = Sact * eWhh1[r*4 + perm[k]];
  }
  const float eb0s = Sact * eb0[r];
  const float eb1s = Sact * eb1[r];

  float dwh0p[4], dwi1p[4], dwh1p[4], wppp[4], dw0row[8];
#pragma unroll
  for (int k = 0; k < 4; ++k) {
    dwh0p[k] = Sact * dWhh0[r*4 + perm[k]];
    dwi1p[k] = Sact * dWih1[r*4 + perm[k]];
    dwh1p[k] = Sact * dWhh1[r*4 + perm[k]];
  }
#pragma unroll
  for (int k = 0; k < 8; ++k) dw0row[k] = dWih0[r*8 + k];
  // fused decoder layer0: W'' = dec_Wih0 @ fc_W (columns permuted), b'' = db0 + dec_Wih0 @ fc_b
#pragma unroll
  for (int k = 0; k < 4; ++k) {
    float s = 0.f;
#pragma unroll
    for (int f = 0; f < 8; ++f) s = fmaf(dw0row[f], fcW[f*4 + perm[k]], s);
    wppp[k] = Sact * s;
  }
  float bcorr = 0.f;
#pragma unroll
  for (int f = 0; f < 8; ++f) bcorr = fmaf(dw0row[f], fcb[f], bcorr);
  const float dbias0 = Sact * db0[r];            // decoder step 0: x0 == 0 (no fc bias)
  const float dbiasR = Sact * (db0[r] + bcorr);
  const float db1s   = Sact * db1[r];

  const int fr = l & 7;
  float fwp[4];
#pragma unroll
  for (int k = 0; k < 4; ++k) fwp[k] = fcW[fr*4 + perm[k]];
  const float fbr = fcb[fr];

  // ---------------- state (h kept as rotated tuple: h?r[k] = h_{perm[k]}) ----------------
  float h0r0=0.f,h0r1=0.f,h0r2=0.f,h0r3=0.f;
  float h1r0=0.f,h1r1=0.f,h1r2=0.f,h1r3=0.f;
  float c0 = 0.f, c1 = 0.f;

  auto actSig = [&](float z) -> float {
    return fmaf(actA, rcp_(1.f + ex2_(z)), actB);
  };
  // gate gather + cell update + tanh: returns new h (own unit, replicated in quad)
  auto cellh = [&](float a, float& c) -> float {
    float ai = QB(a,0), af = QB(a,1), ag = QB(a,2), ao = QB(a,3);
    c = fmaf(af, c, ai * ag);
    float th = fmaf(2.f, rcp_(1.f + ex2_(TS * c)), -1.f);
    return ao * th;
  };

  const float* xp = X + (size_t)e * (TT*FF);

  // encoder layer0: consumes x + h0r tuple, produces next-h0 tuple (n0..n3)
  auto encL0 = [&](const float4 xlo, const float4 xhi,
                   float& n0, float& n1, float& n2, float& n3) {
    float za = fmaf(xlo.x, ewx[0], eb0s);
    za = fmaf(xlo.y, ewx[1], za);
    za = fmaf(xlo.z, ewx[2], za);
    za = fmaf(xlo.w, ewx[3], za);
    float zb = xhi.x * ewx[4];
    zb = fmaf(xhi.y, ewx[5], zb);
    zb = fmaf(xhi.z, ewx[6], zb);
    zb = fmaf(xhi.w, ewx[7], zb);
    za = fmaf(h0r0, ewh0p[0], za);
    zb = fmaf(h0r1, ewh0p[1], zb);
    za = fmaf(h0r2, ewh0p[2], za);
    zb = fmaf(h0r3, ewh0p[3], zb);
    float a = actSig(za + zb);
    float hn = cellh(a, c0);
    n0 = hn; n1 = ROR4F(hn); n2 = ROR8F(hn); n3 = ROR12F(hn);
  };
  // encoder layer1: consumes h0r tuple (prev step's layer0 out) + h1r tuple
  auto encL1 = [&]() {
    float wa = fmaf(h1r0, ewh1p[0], eb1s);
    wa = fmaf(h1r1, ewh1p[1], wa);
    float wb = h1r2 * ewh1p[2];
    wb = fmaf(h1r3, ewh1p[3], wb);
    wa = fmaf(h0r0, ewi1p[0], wa);
    wb = fmaf(h0r1, ewi1p[1], wb);
    wa = fmaf(h0r2, ewi1p[2], wa);
    wb = fmaf(h0r3, ewi1p[3], wb);
    float a1 = actSig(wa + wb);
    float hn1 = cellh(a1, c1);
    h1r0 = hn1; h1r1 = ROR4F(hn1); h1r2 = ROR8F(hn1); h1r3 = ROR12F(hn1);
  };

  // ---------------- encoder: layer0 runs 1 step ahead of layer1 (ILP overlap) ----------------
  float4 pa0 = *(const float4*)(xp + 0), pb0 = *(const float4*)(xp + 4);
  float4 pa1 = *(const float4*)(xp + 8), pb1 = *(const float4*)(xp + 12);
  float4 pa2 = *(const float4*)(xp + 16), pb2 = *(const float4*)(xp + 20);
  float4 pa3 = *(const float4*)(xp + 24), pb3 = *(const float4*)(xp + 28);

  { // t = 0 (layer0 only)
    float n0,n1,n2,n3;
    encL0(pa0, pb0, n0,n1,n2,n3);
    h0r0=n0; h0r1=n1; h0r2=n2; h0r3=n3;
    pa0 = *(const float4*)(xp + 4*FF); pb0 = *(const float4*)(xp + 4*FF + 4);
  }

#define ESTEP(SA, SB, T) do { \
    float n0_,n1_,n2_,n3_; \
    encL0(SA, SB, n0_,n1_,n2_,n3_); \
    encL1(); \
    h0r0=n0_; h0r1=n1_; h0r2=n2_; h0r3=n3_; \
    SA = *(const float4*)(xp + ((T)+4)*FF); \
    SB = *(const float4*)(xp + ((T)+4)*FF + 4); \
  } while(0)
#define ESTEPN(SA, SB) do { \
    float n0_,n1_,n2_,n3_; \
    encL0(SA, SB, n0_,n1_,n2_,n3_); \
    encL1(); \
    h0r0=n0_; h0r1=n1_; h0r2=n2_; h0r3=n3_; \
  } while(0)

#pragma unroll 1
  for (int ib = 1; ib <= 1013; ib += 4) {   // t = 1..1016
    ESTEP(pa1, pb1, ib + 0);
    ESTEP(pa2, pb2, ib + 1);
    ESTEP(pa3, pb3, ib + 2);
    ESTEP(pa0, pb0, ib + 3);
  }
  // t = 1017..1019 (reload x[1021..1023]), then t = 1020..1023, then final layer1
  ESTEP(pa1, pb1, 1017);
  ESTEP(pa2, pb2, 1018);
  ESTEP(pa3, pb3, 1019);
  ESTEPN(pa0, pb0);   // t=1020
  ESTEPN(pa1, pb1);   // t=1021
  ESTEPN(pa2, pb2);   // t=1022
  ESTEPN(pa3, pb3);   // t=1023
  encL1();            // layer1 for t=1023

  // ---------------- decoder: 1024 autoregressive steps ----------------
  float rhr0=0.f, rhr1=0.f, rhr2=0.f, rhr3=0.f;   // relu(h1) tuple; x0==0
  // partials for the upcoming step (computed from current state, off critical path)
  float zh0p = fmaf(h0r0, dwh0p[0], dbias0);
  zh0p = fmaf(h0r1, dwh0p[1], zh0p);
  zh0p = fmaf(h0r2, dwh0p[2], zh0p);
  zh0p = fmaf(h0r3, dwh0p[3], zh0p);
  float zh1p = fmaf(h1r0, dwh1p[0], db1s);
  zh1p = fmaf(h1r1, dwh1p[1], zh1p);
  zh1p = fmaf(h1r2, dwh1p[2], zh1p);
  zh1p = fmaf(h1r3, dwh1p[3], zh1p);

  const bool lo8 = (l < 8);
  float ykeep = 0.f;
  // lanes 0-7 store even t, lanes 8-15 store odd t (y is identical across half-groups)
  float* op2 = out + (size_t)e*(TT*FF) + (size_t)(TT - 1 - (l >> 3))*FF + fr;

#define DSTEP(DO_STORE) do { \
    /* layer0 (fc fused): z = zh0p + rh·W'' */ \
    float za_ = fmaf(rhr0, wppp[0], zh0p); \
    float zb_ = rhr1 * wppp[1]; \
    za_ = fmaf(rhr2, wppp[2], za_); \
    zb_ = fmaf(rhr3, wppp[3], zb_); \
    float a_ = actSig(za_ + zb_); \
    float hn_ = cellh(a_, c0); \
    float n0_ = hn_, n1_ = ROR4F(hn_), n2_ = ROR8F(hn_), n3_ = ROR12F(hn_); \
    /* layer1: z1 = zh1p + n·Wih1 */ \
    float w1a_ = fmaf(n0_, dwi1p[0], zh1p); \
    float w1b_ = n1_ * dwi1p[1]; \
    w1a_ = fmaf(n2_, dwi1p[2], w1a_); \
    w1b_ = fmaf(n3_, dwi1p[3], w1b_); \
    float a1_ = actSig(w1a_ + w1b_); \
    float hn1_ = cellh(a1_, c1); \
    h1r0 = hn1_; h1r1 = ROR4F(hn1_); h1r2 = ROR8F(hn1_); h1r3 = ROR12F(hn1_); \
    h0r0 = n0_; h0r1 = n1_; h0r2 = n2_; h0r3 = n3_; \
    /* next-step partials + y (off critical path) */ \
    zh0p = fmaf(h0r0, dwh0p[0], dbiasR); \
    zh0p = fmaf(h0r1, dwh0p[1], zh0p); \
    zh0p = fmaf(h0r2, dwh0p[2], zh0p); \
    zh0p = fmaf(h0r3, dwh0p[3], zh0p); \
    zh1p = fmaf(h1r0, dwh1p[0], db1s); \
    zh1p = fmaf(h1r1, dwh1p[1], zh1p); \
    zh1p = fmaf(h1r2, dwh1p[2], zh1p); \
    zh1p = fmaf(h1r3, dwh1p[3], zh1p); \
    rhr0 = fmaxf(h1r0, 0.f); rhr1 = fmaxf(h1r1, 0.f); \
    rhr2 = fmaxf(h1r2, 0.f); rhr3 = fmaxf(h1r3, 0.f); \
    float y_ = fmaf(rhr0, fwp[0], fbr); \
    y_ = fmaf(rhr1, fwp[1], y_); \
    y_ = fmaf(rhr2, fwp[2], y_); \
    y_ = fmaf(rhr3, fwp[3], y_); \
    if (DO_STORE) { \
      float yst_ = lo8 ? ykeep : y_; \
      *op2 = yst_; \
      op2 -= 2*FF; \
    } else { \
      ykeep = y_; \
    } \
  } while(0)

#pragma unroll 1
  for (int m = 0; m < TT/2; ++m) {
    DSTEP(false);   // even t: keep y in register
    DSTEP(true);    // odd t: 16-lane coalesced store of two rows
  }
}

extern "C" void kernel_launch(void* const* d_in, const int* in_sizes, int n_in,
                              void* d_out, int out_size, void* d_ws, size_t ws_size,
                              hipStream_t stream) {
  const float* X      = (const float*)d_in[0];
  const float* eWih0  = (const float*)d_in[1];
  const float* eWhh0  = (const float*)d_in[2];
  const float* eb0    = (const float*)d_in[3];
  const float* eWih1  = (const float*)d_in[4];
  const float* eWhh1  = (const float*)d_in[5];
  const float* eb1    = (const float*)d_in[6];
  const float* dWih0  = (const float*)d_in[7];
  const float* dWhh0  = (const float*)d_in[8];
  const float* db0    = (const float*)d_in[9];
  const float* dWih1  = (const float*)d_in[10];
  const float* dWhh1  = (const float*)d_in[11];
  const float* db1    = (const float*)d_in[12];
  const float* fcW    = (const float*)d_in[13];
  const float* fcb    = (const float*)d_in[14];
  float* out = (float*)d_out;

  // 4096 elements x 16 lanes = 65536 threads = 1024 waves (1 per SIMD)
  dim3 grid(256), block(256);
  lstm_ae_kernel<<<grid, block, 0, stream>>>(X, eWih0, eWhh0, eb0, eWih1, eWhh1, eb1,
                                             dWih0, dWhh0, db0, dWih1, dWhh1, db1,
                                             fcW, fcb, out);
}